// Round 10
// baseline (768.214 us; speedup 1.0000x reference)
//
#include <hip/hip_runtime.h>

#define N0v 614400
#define N1v 40960
#define BATCHv 4096

typedef __attribute__((ext_vector_type(8))) short short8;
typedef __attribute__((ext_vector_type(4))) float floatx4;

static __device__ __forceinline__ float flog1p(float v) { return __logf(v + 1.0f); }
static __device__ __forceinline__ float sigf(float v) { return 1.0f / (1.0f + __expf(-v)); }
static __device__ __forceinline__ float tanhfast(float v) {
    return 1.0f - 2.0f / (__expf(2.0f * v) + 1.0f);
}
static __device__ __forceinline__ unsigned short f2bf(float f) {
    union { float f; unsigned u; } v; v.f = f;
    unsigned r = v.u + 0x7FFFu + ((v.u >> 16) & 1u);   // RNE
    return (unsigned short)(r >> 16);
}
static __device__ __forceinline__ float bf2f(unsigned short u) {
    return __uint_as_float(((unsigned)u) << 16);
}

// ---------------------------------------------------------------------------
// Weight pre-convert: fp32 -> bf16 copies in ws, plus bsum = b_ih + b_hh.
// ---------------------------------------------------------------------------
__global__ __launch_bounds__(256) void cvt_weights_kernel(
    const float* __restrict__ Wp, const float* __restrict__ Ws0,
    const float* __restrict__ Wn0, const float* __restrict__ Wih,
    const float* __restrict__ Whh, const float* __restrict__ bih,
    const float* __restrict__ bhh,
    unsigned short* __restrict__ Wpb, unsigned short* __restrict__ Ws0b,
    unsigned short* __restrict__ Wn0b, unsigned short* __restrict__ Wihb,
    unsigned short* __restrict__ Whhb, float* __restrict__ bsum)
{
    const int g = blockIdx.x * 256 + threadIdx.x;
    if (g < 16384)            Wpb[g] = f2bf(Wp[g]);
    else if (g < 49152)       Ws0b[g - 16384] = f2bf(Ws0[g - 16384]);
    else if (g < 81920)       Wn0b[g - 49152] = f2bf(Wn0[g - 49152]);
    else if (g < 344064)      Wihb[g - 81920] = f2bf(Wih[g - 81920]);
    else if (g < 606208)      Whhb[g - 344064] = f2bf(Whh[g - 344064]);
    else if (g < 607232) { const int i = g - 606208; bsum[i] = bih[i] + bhh[i]; }
}

// ---------------------------------------------------------------------------
// BIG-WS PATH, phase 1: dense hp = relu(log1p(x) @ Wp^T + bp) for ALL N0 rows.
// Coalesced A; staged LDS; bit-identical to gathered version's values.
// ---------------------------------------------------------------------------
__global__ __launch_bounds__(256) void pool_dense_kernel(
    const float* __restrict__ x, const unsigned short* __restrict__ Wpb,
    const float* __restrict__ bp, unsigned short* __restrict__ hpb)
{
    __shared__ unsigned short smem[64 * 72 + 128 * 72];
    unsigned short* aT = smem;
    unsigned short* wT = smem + 64 * 72;

    const int tid = threadIdx.x;
    const int m0 = blockIdx.x * 64;
    const int lane = tid & 63, wv = tid >> 6;
    const int ml = lane & 15, q = lane >> 4, qk = q * 8;

    floatx4 acc[8];
#pragma unroll
    for (int ct = 0; ct < 8; ++ct) acc[ct] = (floatx4){0.f, 0.f, 0.f, 0.f};

    for (int kc = 0; kc < 2; ++kc) {
        __syncthreads();
        for (int i = tid; i < 512; i += 256) {            // A: 64 rows x 64 k
            const int row = i >> 3, seg = i & 7;
            const float* s = x + (size_t)(m0 + row) * 128 + kc * 64 + seg * 8;
            const float4 f0 = *(const float4*)s;
            const float4 f1 = *(const float4*)(s + 4);
            short8 o;
            o[0] = (short)f2bf(flog1p(f0.x)); o[1] = (short)f2bf(flog1p(f0.y));
            o[2] = (short)f2bf(flog1p(f0.z)); o[3] = (short)f2bf(flog1p(f0.w));
            o[4] = (short)f2bf(flog1p(f1.x)); o[5] = (short)f2bf(flog1p(f1.y));
            o[6] = (short)f2bf(flog1p(f1.z)); o[7] = (short)f2bf(flog1p(f1.w));
            *(short8*)&aT[row * 72 + seg * 8] = o;
        }
        for (int i = tid; i < 1024; i += 256) {           // W: 128 rows x 64 k
            const int row = i >> 3, seg = i & 7;
            *(short8*)&wT[row * 72 + seg * 8] =
                *(const short8*)&Wpb[(size_t)row * 128 + kc * 64 + seg * 8];
        }
        __syncthreads();
#pragma unroll
        for (int k0 = 0; k0 < 64; k0 += 32) {
            const short8 a = *(const short8*)&aT[(wv * 16 + ml) * 72 + k0 + qk];
#pragma unroll
            for (int ct = 0; ct < 8; ++ct) {
                const short8 b = *(const short8*)&wT[(ct * 16 + ml) * 72 + k0 + qk];
                acc[ct] = __builtin_amdgcn_mfma_f32_16x16x32_bf16(a, b, acc[ct], 0, 0, 0);
            }
        }
    }
#pragma unroll
    for (int ct = 0; ct < 8; ++ct) {
        const int col = ct * 16 + ml;
        const float bb = bp[col];
#pragma unroll
        for (int r = 0; r < 4; ++r) {
            const int row = wv * 16 + q * 4 + r;
            hpb[(size_t)(m0 + row) * 128 + col] = f2bf(fmaxf(acc[ct][r] + bb, 0.0f));
        }
    }
}

// ---------------------------------------------------------------------------
// BIG-WS PATH, phase 2: hnb[g] = elementwise-max over hp[nbr0[g][0..14]].
// One wave per node; coalesced 256 B row reads; bf16 max == max then bf16.
// ---------------------------------------------------------------------------
__global__ __launch_bounds__(256) void pool_gather_kernel(
    const unsigned short* __restrict__ hpb, const int* __restrict__ nbr0,
    unsigned short* __restrict__ hnb)
{
    const int g = blockIdx.x * 256 + threadIdx.x;      // node*64 + lanepos
    const int node = g >> 6, lp = g & 63;
    const unsigned* hp32 = (const unsigned*)hpb;
    float mlo = 0.0f, mhi = 0.0f;                      // relu outputs >= 0
#pragma unroll
    for (int j = 0; j < 15; ++j) {
        const int idx = nbr0[node * 15 + j];
        const unsigned v = hp32[(size_t)idx * 64 + lp];
        mlo = fmaxf(mlo, bf2f((unsigned short)(v & 0xffffu)));
        mhi = fmaxf(mhi, bf2f((unsigned short)(v >> 16)));
    }
    const unsigned lo = __float_as_uint(mlo) >> 16;
    const unsigned hi = __float_as_uint(mhi) & 0xffff0000u;
    ((unsigned*)hnb)[(size_t)node * 64 + lp] = hi | lo;
}

// ---------------------------------------------------------------------------
// SMALL-WS FALLBACK: R1's proven pool-SAGE (staged A+W, LDS atomicMax).
// ---------------------------------------------------------------------------
__global__ __launch_bounds__(256) void pool_max_kernel(
    const float* __restrict__ x, const int* __restrict__ nbr0,
    const unsigned short* __restrict__ Wpb, const float* __restrict__ bp,
    unsigned short* __restrict__ hnb)
{
    __shared__ unsigned short smem[64 * 72 + 128 * 72];
    __shared__ unsigned red[512];
    __shared__ int nodes[64];
    unsigned short* aT = smem;
    unsigned short* wT = smem + 64 * 72;

    const int tid = threadIdx.x;
    const size_t base = (size_t)blockIdx.x * 60;
    if (tid < 64) nodes[tid] = (tid < 60) ? nbr0[base + tid] : 0;
    for (int i = tid; i < 512; i += 256) red[i] = 0u;

    const int lane = tid & 63, wv = tid >> 6;
    const int ml = lane & 15, q = lane >> 4, qk = q * 8;

    floatx4 acc[8];
#pragma unroll
    for (int ct = 0; ct < 8; ++ct) acc[ct] = (floatx4){0.f, 0.f, 0.f, 0.f};

    for (int kc = 0; kc < 2; ++kc) {
        __syncthreads();
        for (int i = tid; i < 512; i += 256) {
            const int row = i >> 3, seg = i & 7;
            short8 o = {0, 0, 0, 0, 0, 0, 0, 0};
            if (row < 60) {
                const float* s = x + (size_t)nodes[row] * 128 + kc * 64 + seg * 8;
                const float4 f0 = *(const float4*)s;
                const float4 f1 = *(const float4*)(s + 4);
                o[0] = (short)f2bf(flog1p(f0.x)); o[1] = (short)f2bf(flog1p(f0.y));
                o[2] = (short)f2bf(flog1p(f0.z)); o[3] = (short)f2bf(flog1p(f0.w));
                o[4] = (short)f2bf(flog1p(f1.x)); o[5] = (short)f2bf(flog1p(f1.y));
                o[6] = (short)f2bf(flog1p(f1.z)); o[7] = (short)f2bf(flog1p(f1.w));
            }
            *(short8*)&aT[row * 72 + seg * 8] = o;
        }
        for (int i = tid; i < 1024; i += 256) {
            const int row = i >> 3, seg = i & 7;
            *(short8*)&wT[row * 72 + seg * 8] =
                *(const short8*)&Wpb[(size_t)row * 128 + kc * 64 + seg * 8];
        }
        __syncthreads();
#pragma unroll
        for (int k0 = 0; k0 < 64; k0 += 32) {
            const short8 a = *(const short8*)&aT[(wv * 16 + ml) * 72 + k0 + qk];
#pragma unroll
            for (int ct = 0; ct < 8; ++ct) {
                const short8 b = *(const short8*)&wT[(ct * 16 + ml) * 72 + k0 + qk];
                acc[ct] = __builtin_amdgcn_mfma_f32_16x16x32_bf16(a, b, acc[ct], 0, 0, 0);
            }
        }
    }
    __syncthreads();
#pragma unroll
    for (int ct = 0; ct < 8; ++ct) {
        const int col = ct * 16 + ml;
        const float bb = bp[col];
#pragma unroll
        for (int r = 0; r < 4; ++r) {
            const int row = wv * 16 + q * 4 + r;
            if (row < 60) {
                const float v = fmaxf(acc[ct][r] + bb, 0.0f);
                atomicMax(&red[(row / 15) * 128 + col], __float_as_uint(v));
            }
        }
    }
    __syncthreads();
    for (int i = tid; i < 512; i += 256)
        hnb[(size_t)blockIdx.x * 512 + i] = f2bf(__uint_as_float(red[i]));
}

// ---------------------------------------------------------------------------
// Stage B: h0 = [log1p(x[:N1]) | h_neigh] @ [Ws0|Wn0]^T + b0 (R1-proven),
// stored bf16 pre-BN, fused per-column sum/sumsq partials.
// ---------------------------------------------------------------------------
__global__ __launch_bounds__(256) void h0_kernel(
    const float* __restrict__ x, const unsigned short* __restrict__ hnb,
    const unsigned short* __restrict__ Ws0b, const unsigned short* __restrict__ Wn0b,
    const float* __restrict__ b0, unsigned short* __restrict__ h0bf,
    float* __restrict__ bn_sum, float* __restrict__ bn_sq)
{
    __shared__ unsigned short smem[64 * 72 + 128 * 72];
    unsigned short* aT = smem;
    unsigned short* wT = smem + 64 * 72;

    const int tid = threadIdx.x;
    const int m0 = blockIdx.x * 64, c0 = blockIdx.y * 128;
    const int lane = tid & 63, wv = tid >> 6;
    const int ml = lane & 15, q = lane >> 4, qk = q * 8;

    floatx4 acc[8];
#pragma unroll
    for (int ct = 0; ct < 8; ++ct) acc[ct] = (floatx4){0.f, 0.f, 0.f, 0.f};

    for (int kc = 0; kc < 4; ++kc) {
        __syncthreads();
        for (int i = tid; i < 512; i += 256) {
            const int row = i >> 3, seg = i & 7;
            const int k = kc * 64 + seg * 8;
            if (kc < 2) {
                const float* s = x + (size_t)(m0 + row) * 128 + k;
                const float4 f0 = *(const float4*)s;
                const float4 f1 = *(const float4*)(s + 4);
                short8 o;
                o[0] = (short)f2bf(flog1p(f0.x)); o[1] = (short)f2bf(flog1p(f0.y));
                o[2] = (short)f2bf(flog1p(f0.z)); o[3] = (short)f2bf(flog1p(f0.w));
                o[4] = (short)f2bf(flog1p(f1.x)); o[5] = (short)f2bf(flog1p(f1.y));
                o[6] = (short)f2bf(flog1p(f1.z)); o[7] = (short)f2bf(flog1p(f1.w));
                *(short8*)&aT[row * 72 + seg * 8] = o;
            } else {
                *(short8*)&aT[row * 72 + seg * 8] =
                    *(const short8*)&hnb[(size_t)(m0 + row) * 128 + (k - 128)];
            }
        }
        for (int i = tid; i < 1024; i += 256) {
            const int row = i >> 3, seg = i & 7;
            const int k = kc * 64 + seg * 8;
            const size_t cg = (size_t)(c0 + row);
            *(short8*)&wT[row * 72 + seg * 8] = (kc < 2)
                ? *(const short8*)&Ws0b[cg * 128 + k]
                : *(const short8*)&Wn0b[cg * 128 + (k - 128)];
        }
        __syncthreads();
#pragma unroll
        for (int k0 = 0; k0 < 64; k0 += 32) {
            const short8 a = *(const short8*)&aT[(wv * 16 + ml) * 72 + k0 + qk];
#pragma unroll
            for (int ct = 0; ct < 8; ++ct) {
                const short8 b = *(const short8*)&wT[(ct * 16 + ml) * 72 + k0 + qk];
                acc[ct] = __builtin_amdgcn_mfma_f32_16x16x32_bf16(a, b, acc[ct], 0, 0, 0);
            }
        }
    }
    __syncthreads();
    float* scr = (float*)smem;   // 4096 floats = 16 KB
#pragma unroll
    for (int ct = 0; ct < 8; ++ct) {
        const int col = ct * 16 + ml, cg = c0 + col;
        const float bb = b0[cg];
        float s = 0.f, sq = 0.f;
#pragma unroll
        for (int r = 0; r < 4; ++r) {
            const int row = wv * 16 + q * 4 + r;
            const float v = acc[ct][r] + bb;
            h0bf[(size_t)(m0 + row) * 256 + cg] = f2bf(v);
            s += v; sq += v * v;
        }
        scr[(wv * 4 + q) * 128 + col] = s;
        scr[2048 + (wv * 4 + q) * 128 + col] = sq;
    }
    __syncthreads();
    if (tid < 128) {
        float s = 0.f, sq = 0.f;
#pragma unroll
        for (int j = 0; j < 16; ++j) {
            s += scr[j * 128 + tid];
            sq += scr[2048 + j * 128 + tid];
        }
        atomicAdd(&bn_sum[c0 + tid], s);
        atomicAdd(&bn_sq[c0 + tid], sq);
    }
}

// ---------------------------------------------------------------------------
// bn_apply with stats folded in (each block recomputes scale/shift in f32 —
// same formula as the old bn_stats -> bit-identical).
// ---------------------------------------------------------------------------
__global__ __launch_bounds__(256) void bn_apply_kernel(
    const unsigned short* __restrict__ h0bf, const float* __restrict__ bn_sum,
    const float* __restrict__ bn_sq, const float* __restrict__ gamma,
    const float* __restrict__ beta, unsigned short* __restrict__ h0nbf)
{
    __shared__ float sc[256], sh[256];
    const int tid = threadIdx.x;
    {
        const float inv_n = 1.0f / (float)N1v;
        const float mu = bn_sum[tid] * inv_n;
        const float var = bn_sq[tid] * inv_n - mu * mu;
        const float rs = rsqrtf(var + 1e-5f);
        const float s = rs * gamma[tid];
        sc[tid] = s;
        sh[tid] = beta[tid] - mu * s;
    }
    __syncthreads();
    const int gid = blockIdx.x * 256 + tid;   // over N1*256/8
    const int c0 = (gid * 8) & 255;
    const short8 v = *(const short8*)&h0bf[(size_t)gid * 8];
    short8 o;
#pragma unroll
    for (int j = 0; j < 8; ++j) {
        const float f = bf2f((unsigned short)v[j]);
        o[j] = (short)f2bf(fmaxf(fmaf(f, sc[c0 + j], sh[c0 + j]), 0.0f));
    }
    *(short8*)&h0nbf[(size_t)gid * 8] = o;
}

// ---------------------------------------------------------------------------
// Fused LSTM step, MAX-OCCUPANCY tiling: grid (64,32) = 2048 blocks = 8
// blocks/CU, 32 waves/CU (vs R9's 4/16). Block = 64 rows x 8 h-cols x 4
// gates = 32 gate-cols (2 MFMA col-tiles, acc[2]). Tile ct covers gates
// {2ct, 2ct+1}: col-in-tile = (gate&1)*8 + hc. A thread (lane ml) holds
// gates {g0, g0+2} (g0=ml>>3) for one (row, hc); partner lane ml^8 (same
// rows/hc) holds the complement -> two shfl_xor(8) deliver all 4 gates.
// Shfl moves exact bits; per-output MFMA K-sequence unchanged (64-k chunks,
// K order 0,32,...,480) -> bit-identical. LDS 14.1 KB. t=0 skips h_prev.
// ---------------------------------------------------------------------------
__global__ __launch_bounds__(256) void lstm_step_kernel(
    const unsigned short* __restrict__ h0nbf, const int* __restrict__ nbr1,
    const unsigned short* __restrict__ hbprev, const unsigned short* __restrict__ Wihb,
    const unsigned short* __restrict__ Whhb, const float* __restrict__ bsum,
    float* __restrict__ cst, unsigned short* __restrict__ hb, int t)
{
    __shared__ unsigned short aT[64 * 72];    // 9,216 B
    __shared__ unsigned short wT[32 * 72];    // 4,608 B
    __shared__ int nodes[64];

    const int tid = threadIdx.x;
    const int m0 = blockIdx.x * 64, c0h = blockIdx.y * 8;
    const int lane = tid & 63, wv = tid >> 6;
    const int ml = lane & 15, q = lane >> 4, qk = q * 8;

    if (tid < 64) nodes[tid] = nbr1[(size_t)(m0 + tid) * 10 + t];

    floatx4 acc[2];
#pragma unroll
    for (int ct = 0; ct < 2; ++ct) acc[ct] = (floatx4){0.f, 0.f, 0.f, 0.f};

    const int kcN = (t == 0) ? 4 : 8;   // 64-k chunks; h_prev == 0 at t=0
    for (int kc = 0; kc < kcN; ++kc) {
        __syncthreads();
        for (int i = tid; i < 512; i += 256) {            // A: 64 rows x 64 k
            const int row = i >> 3, seg = i & 7;
            const int k = kc * 64 + seg * 8;
            *(short8*)&aT[row * 72 + seg * 8] = (kc < 4)
                ? *(const short8*)&h0nbf[(size_t)nodes[row] * 256 + k]
                : *(const short8*)&hbprev[(size_t)(m0 + row) * 256 + (k - 256)];
        }
        {                                                 // W: 32 gate-rows x 64 k
            const int i = tid, row = i >> 3, seg = i & 7; // one iter (256 slots)
            const int k = kc * 64 + seg * 8;
            // local row -> (gate, hc): tile ct=row>>4, j=row&15,
            // gate = ct*2 + (j>>3), hc = j&7
            const int j = row & 15;
            const size_t wr = (size_t)(((row >> 4) * 2 + (j >> 3)) * 256 + c0h + (j & 7));
            *(short8*)&wT[row * 72 + seg * 8] = (kc < 4)
                ? *(const short8*)&Wihb[wr * 256 + k]
                : *(const short8*)&Whhb[wr * 256 + (k - 256)];
        }
        __syncthreads();
#pragma unroll
        for (int k0 = 0; k0 < 64; k0 += 32) {
            const short8 a = *(const short8*)&aT[(wv * 16 + ml) * 72 + k0 + qk];
#pragma unroll
            for (int ct = 0; ct < 2; ++ct) {
                const short8 b = *(const short8*)&wT[(ct * 16 + ml) * 72 + k0 + qk];
                acc[ct] = __builtin_amdgcn_mfma_f32_16x16x32_bf16(a, b, acc[ct], 0, 0, 0);
            }
        }
    }
    // pointwise: lane holds gates {g0, g0+2}; partner ml^8 has {1-g0, 3-g0}.
    const int g0 = ml >> 3;            // 0 or 1
    const int hcol = c0h + (ml & 7);
    const float bi = bsum[hcol];
    const float bf_ = bsum[256 + hcol];
    const float bg = bsum[512 + hcol];
    const float bo = bsum[768 + hcol];
#pragma unroll
    for (int r = 0; r < 4; ++r) {
        const int row = wv * 16 + q * 4 + r;
        const float y0 = acc[0][r];            // gate g0   (i or f)
        const float y1 = acc[1][r];            // gate g0+2 (g or o)
        const float z0 = __shfl_xor(y0, 8);    // gate 1-g0
        const float z1 = __shfl_xor(y1, 8);    // gate 3-g0
        const float gi = ((g0 == 0) ? y0 : z0) + bi;
        const float gf = ((g0 == 0) ? z0 : y0) + bf_;
        const float gg = ((g0 == 0) ? y1 : z1) + bg;
        const float go = ((g0 == 0) ? z1 : y1) + bo;
        float c = sigf(gi) * tanhfast(gg);
        const size_t idx = (size_t)(m0 + row) * 256 + hcol;
        if (t > 0) c += sigf(gf) * cst[idx];
        if (g0 == 0) {
            cst[idx] = c;
            hb[idx] = f2bf(sigf(go) * tanhfast(c));
        }
    }
}

// Stage E: out = h0n[:B] @ W_self1^T + hT @ W_neigh1^T + b1   [4096 x 32]
__global__ __launch_bounds__(256) void out_kernel(
    const unsigned short* __restrict__ h0nbf, const unsigned short* __restrict__ hTb,
    const float* __restrict__ Ws1, const float* __restrict__ Wn1,
    const float* __restrict__ b1, float* __restrict__ out)
{
    const int gid = blockIdx.x * 256 + threadIdx.x;   // < 4096*32
    const int row = gid >> 5, c = gid & 31;
    const unsigned short* a0 = h0nbf + (size_t)row * 256;
    const unsigned short* a1 = hTb + (size_t)row * 256;
    const float* w0 = Ws1 + (size_t)c * 256;
    const float* w1 = Wn1 + (size_t)c * 256;
    float s = b1[c];
#pragma unroll 4
    for (int k8 = 0; k8 < 32; ++k8) {
        const short8 av = *(const short8*)&a0[k8 * 8];
        const short8 bv = *(const short8*)&a1[k8 * 8];
        const float4 wa0 = *(const float4*)&w0[k8 * 8];
        const float4 wa1 = *(const float4*)&w0[k8 * 8 + 4];
        const float4 wb0 = *(const float4*)&w1[k8 * 8];
        const float4 wb1 = *(const float4*)&w1[k8 * 8 + 4];
        s += bf2f((unsigned short)av[0]) * wa0.x + bf2f((unsigned short)av[1]) * wa0.y;
        s += bf2f((unsigned short)av[2]) * wa0.z + bf2f((unsigned short)av[3]) * wa0.w;
        s += bf2f((unsigned short)av[4]) * wa1.x + bf2f((unsigned short)av[5]) * wa1.y;
        s += bf2f((unsigned short)av[6]) * wa1.z + bf2f((unsigned short)av[7]) * wa1.w;
        s += bf2f((unsigned short)bv[0]) * wb0.x + bf2f((unsigned short)bv[1]) * wb0.y;
        s += bf2f((unsigned short)bv[2]) * wb0.z + bf2f((unsigned short)bv[3]) * wb0.w;
        s += bf2f((unsigned short)bv[4]) * wb1.x + bf2f((unsigned short)bv[5]) * wb1.y;
        s += bf2f((unsigned short)bv[6]) * wb1.z + bf2f((unsigned short)bv[7]) * wb1.w;
    }
    out[gid] = s;
}

extern "C" void kernel_launch(void* const* d_in, const int* in_sizes, int n_in,
                              void* d_out, int out_size, void* d_ws, size_t ws_size,
                              hipStream_t stream)
{
    const float* x        = (const float*)d_in[0];
    const int*   nbr0     = (const int*)d_in[1];
    const int*   nbr1     = (const int*)d_in[2];
    const float* W_pool   = (const float*)d_in[3];
    const float* b_pool   = (const float*)d_in[4];
    const float* W_self0  = (const float*)d_in[5];
    const float* W_neigh0 = (const float*)d_in[6];
    const float* b0       = (const float*)d_in[7];
    const float* gamma0   = (const float*)d_in[8];
    const float* beta0    = (const float*)d_in[9];
    const float* W_ih     = (const float*)d_in[10];
    const float* W_hh     = (const float*)d_in[11];
    const float* b_ih     = (const float*)d_in[12];
    const float* b_hh     = (const float*)d_in[13];
    const float* W_self1  = (const float*)d_in[14];
    const float* W_neigh1 = (const float*)d_in[15];
    const float* b1       = (const float*)d_in[16];
    float* out = (float*)d_out;

    char* ws = (char*)d_ws;
    const size_t NEED_BIG = 168990720;   // big path: hnb + hp(157MB, aliased) + weights
    const bool big = (ws_size >= NEED_BIG);

    unsigned short *h0bf, *hnb, *h0nbf, *hb0, *hb1, *Wpb, *Ws0b, *Wn0b, *Wihb, *Whhb, *hpb;
    float *cst, *bsum, *bn_sum, *bn_sq;

    if (big) {
        hnb   = (unsigned short*)(ws);                    // 10,485,760
        hpb   = (unsigned short*)(ws + 10485760);         // 157,286,400 (dead after gather)
        h0bf  = (unsigned short*)(ws + 10485760);         //  20,971,520 (alias)
        h0nbf = (unsigned short*)(ws + 31457280);         //  20,971,520 (alias)
        cst   = (float*)         (ws + 52428800);         //   4,194,304 (alias)
        hb0   = (unsigned short*)(ws + 56623104);         //   2,097,152 (alias)
        hb1   = (unsigned short*)(ws + 58720256);         //   2,097,152 (alias)
        Wpb   = (unsigned short*)(ws + 167772160);
        Ws0b  = (unsigned short*)(ws + 167804928);
        Wn0b  = (unsigned short*)(ws + 167870464);
        Wihb  = (unsigned short*)(ws + 167936000);
        Whhb  = (unsigned short*)(ws + 168460288);
        bsum  = (float*)         (ws + 168984576);
        bn_sum= (float*)         (ws + 168988672);
        bn_sq = (float*)         (ws + 168989696);
    } else {
        h0bf  = (unsigned short*)(ws);
        hnb   = (unsigned short*)(ws + 20971520);
        h0nbf = (unsigned short*)(ws + 31457280);
        cst   = (float*)         (ws + 52428800);
        hb0   = (unsigned short*)(ws + 56623104);
        hb1   = (unsigned short*)(ws + 58720256);
        Wpb   = (unsigned short*)(ws + 60817408);
        Ws0b  = (unsigned short*)(ws + 60850176);
        Wn0b  = (unsigned short*)(ws + 60915712);
        Wihb  = (unsigned short*)(ws + 60981248);
        Whhb  = (unsigned short*)(ws + 61505536);
        bsum  = (float*)         (ws + 62029824);
        bn_sum= (float*)         (ws + 62033920);
        bn_sq = (float*)         (ws + 62034944);
        hpb   = 0;
    }

    hipMemsetAsync(bn_sum, 0, 2048, stream);        // bn_sum + bn_sq (adjacent)

    cvt_weights_kernel<<<2372, 256, 0, stream>>>(W_pool, W_self0, W_neigh0, W_ih, W_hh,
                                                 b_ih, b_hh, Wpb, Ws0b, Wn0b, Wihb, Whhb, bsum);
    if (big) {
        pool_dense_kernel<<<N0v / 64, 256, 0, stream>>>(x, Wpb, b_pool, hpb);
        pool_gather_kernel<<<(N1v * 64) / 256, 256, 0, stream>>>(hpb, nbr0, hnb);
    } else {
        pool_max_kernel<<<N1v / 4, 256, 0, stream>>>(x, nbr0, Wpb, b_pool, hnb);
    }
    h0_kernel<<<dim3(N1v / 64, 2), 256, 0, stream>>>(x, hnb, Ws0b, Wn0b, b0,
                                                     h0bf, bn_sum, bn_sq);
    bn_apply_kernel<<<(N1v * 256 / 8) / 256, 256, 0, stream>>>(h0bf, bn_sum, bn_sq,
                                                               gamma0, beta0, h0nbf);

    for (int t = 0; t < 10; ++t) {
        const unsigned short* hp = (t & 1) ? hb1 : hb0;
        unsigned short*       hn = (t & 1) ? hb0 : hb1;
        lstm_step_kernel<<<dim3(BATCHv / 64, 32), 256, 0, stream>>>(
            h0nbf, nbr1, hp, Wihb, Whhb, bsum, cst, hn, t);
    }
    // t=9 wrote hb0 -> final hidden state
    out_kernel<<<(BATCHv * 32) / 256, 256, 0, stream>>>(h0nbf, hb0, W_self1, W_neigh1, b1, out);
}

// Round 11
// 740.255 us; speedup vs baseline: 1.0378x; 1.0378x over previous
//
#include <hip/hip_runtime.h>

#define N0v 614400
#define N1v 40960
#define BATCHv 4096

typedef __attribute__((ext_vector_type(8))) short short8;
typedef __attribute__((ext_vector_type(4))) float floatx4;

static __device__ __forceinline__ float flog1p(float v) { return __logf(v + 1.0f); }
static __device__ __forceinline__ float sigf(float v) { return 1.0f / (1.0f + __expf(-v)); }
static __device__ __forceinline__ float tanhfast(float v) {
    return 1.0f - 2.0f / (__expf(2.0f * v) + 1.0f);
}
static __device__ __forceinline__ unsigned short f2bf(float f) {
    union { float f; unsigned u; } v; v.f = f;
    unsigned r = v.u + 0x7FFFu + ((v.u >> 16) & 1u);   // RNE
    return (unsigned short)(r >> 16);
}
static __device__ __forceinline__ float bf2f(unsigned short u) {
    return __uint_as_float(((unsigned)u) << 16);
}

// ---------------------------------------------------------------------------
// Weight pre-convert: fp32 -> bf16 copies in ws, bsum = b_ih + b_hh, and
// zero-init of bn_sum/bn_sq (512 floats) folded in -> no memset dispatch.
// 607744 elements -> grid 2374 x 256.
// ---------------------------------------------------------------------------
__global__ __launch_bounds__(256) void cvt_weights_kernel(
    const float* __restrict__ Wp, const float* __restrict__ Ws0,
    const float* __restrict__ Wn0, const float* __restrict__ Wih,
    const float* __restrict__ Whh, const float* __restrict__ bih,
    const float* __restrict__ bhh,
    unsigned short* __restrict__ Wpb, unsigned short* __restrict__ Ws0b,
    unsigned short* __restrict__ Wn0b, unsigned short* __restrict__ Wihb,
    unsigned short* __restrict__ Whhb, float* __restrict__ bsum,
    float* __restrict__ bnz)
{
    const int g = blockIdx.x * 256 + threadIdx.x;
    if (g < 16384)            Wpb[g] = f2bf(Wp[g]);
    else if (g < 49152)       Ws0b[g - 16384] = f2bf(Ws0[g - 16384]);
    else if (g < 81920)       Wn0b[g - 49152] = f2bf(Wn0[g - 49152]);
    else if (g < 344064)      Wihb[g - 81920] = f2bf(Wih[g - 81920]);
    else if (g < 606208)      Whhb[g - 344064] = f2bf(Whh[g - 344064]);
    else if (g < 607232) { const int i = g - 606208; bsum[i] = bih[i] + bhh[i]; }
    else if (g < 607744)      bnz[g - 607232] = 0.0f;   // bn_sum + bn_sq
}

// ---------------------------------------------------------------------------
// BIG-WS PATH, phase 1: dense hp = relu(log1p(x) @ Wp^T + bp) for ALL N0 rows.
// Coalesced A; staged LDS; bit-identical to gathered version's values.
// ---------------------------------------------------------------------------
__global__ __launch_bounds__(256) void pool_dense_kernel(
    const float* __restrict__ x, const unsigned short* __restrict__ Wpb,
    const float* __restrict__ bp, unsigned short* __restrict__ hpb)
{
    __shared__ unsigned short smem[64 * 72 + 128 * 72];
    unsigned short* aT = smem;
    unsigned short* wT = smem + 64 * 72;

    const int tid = threadIdx.x;
    const int m0 = blockIdx.x * 64;
    const int lane = tid & 63, wv = tid >> 6;
    const int ml = lane & 15, q = lane >> 4, qk = q * 8;

    floatx4 acc[8];
#pragma unroll
    for (int ct = 0; ct < 8; ++ct) acc[ct] = (floatx4){0.f, 0.f, 0.f, 0.f};

    for (int kc = 0; kc < 2; ++kc) {
        __syncthreads();
        for (int i = tid; i < 512; i += 256) {            // A: 64 rows x 64 k
            const int row = i >> 3, seg = i & 7;
            const float* s = x + (size_t)(m0 + row) * 128 + kc * 64 + seg * 8;
            const float4 f0 = *(const float4*)s;
            const float4 f1 = *(const float4*)(s + 4);
            short8 o;
            o[0] = (short)f2bf(flog1p(f0.x)); o[1] = (short)f2bf(flog1p(f0.y));
            o[2] = (short)f2bf(flog1p(f0.z)); o[3] = (short)f2bf(flog1p(f0.w));
            o[4] = (short)f2bf(flog1p(f1.x)); o[5] = (short)f2bf(flog1p(f1.y));
            o[6] = (short)f2bf(flog1p(f1.z)); o[7] = (short)f2bf(flog1p(f1.w));
            *(short8*)&aT[row * 72 + seg * 8] = o;
        }
        for (int i = tid; i < 1024; i += 256) {           // W: 128 rows x 64 k
            const int row = i >> 3, seg = i & 7;
            *(short8*)&wT[row * 72 + seg * 8] =
                *(const short8*)&Wpb[(size_t)row * 128 + kc * 64 + seg * 8];
        }
        __syncthreads();
#pragma unroll
        for (int k0 = 0; k0 < 64; k0 += 32) {
            const short8 a = *(const short8*)&aT[(wv * 16 + ml) * 72 + k0 + qk];
#pragma unroll
            for (int ct = 0; ct < 8; ++ct) {
                const short8 b = *(const short8*)&wT[(ct * 16 + ml) * 72 + k0 + qk];
                acc[ct] = __builtin_amdgcn_mfma_f32_16x16x32_bf16(a, b, acc[ct], 0, 0, 0);
            }
        }
    }
#pragma unroll
    for (int ct = 0; ct < 8; ++ct) {
        const int col = ct * 16 + ml;
        const float bb = bp[col];
#pragma unroll
        for (int r = 0; r < 4; ++r) {
            const int row = wv * 16 + q * 4 + r;
            hpb[(size_t)(m0 + row) * 128 + col] = f2bf(fmaxf(acc[ct][r] + bb, 0.0f));
        }
    }
}

// ---------------------------------------------------------------------------
// BIG-WS PATH, phase 2: hnb[g] = elementwise-max over hp[nbr0[g][0..14]].
// One wave per node; coalesced 256 B row reads; bf16 max == max then bf16.
// ---------------------------------------------------------------------------
__global__ __launch_bounds__(256) void pool_gather_kernel(
    const unsigned short* __restrict__ hpb, const int* __restrict__ nbr0,
    unsigned short* __restrict__ hnb)
{
    const int g = blockIdx.x * 256 + threadIdx.x;      // node*64 + lanepos
    const int node = g >> 6, lp = g & 63;
    const unsigned* hp32 = (const unsigned*)hpb;
    float mlo = 0.0f, mhi = 0.0f;                      // relu outputs >= 0
#pragma unroll
    for (int j = 0; j < 15; ++j) {
        const int idx = nbr0[node * 15 + j];
        const unsigned v = hp32[(size_t)idx * 64 + lp];
        mlo = fmaxf(mlo, bf2f((unsigned short)(v & 0xffffu)));
        mhi = fmaxf(mhi, bf2f((unsigned short)(v >> 16)));
    }
    const unsigned lo = __float_as_uint(mlo) >> 16;
    const unsigned hi = __float_as_uint(mhi) & 0xffff0000u;
    ((unsigned*)hnb)[(size_t)node * 64 + lp] = hi | lo;
}

// ---------------------------------------------------------------------------
// SMALL-WS FALLBACK: R1's proven pool-SAGE (staged A+W, LDS atomicMax).
// ---------------------------------------------------------------------------
__global__ __launch_bounds__(256) void pool_max_kernel(
    const float* __restrict__ x, const int* __restrict__ nbr0,
    const unsigned short* __restrict__ Wpb, const float* __restrict__ bp,
    unsigned short* __restrict__ hnb)
{
    __shared__ unsigned short smem[64 * 72 + 128 * 72];
    __shared__ unsigned red[512];
    __shared__ int nodes[64];
    unsigned short* aT = smem;
    unsigned short* wT = smem + 64 * 72;

    const int tid = threadIdx.x;
    const size_t base = (size_t)blockIdx.x * 60;
    if (tid < 64) nodes[tid] = (tid < 60) ? nbr0[base + tid] : 0;
    for (int i = tid; i < 512; i += 256) red[i] = 0u;

    const int lane = tid & 63, wv = tid >> 6;
    const int ml = lane & 15, q = lane >> 4, qk = q * 8;

    floatx4 acc[8];
#pragma unroll
    for (int ct = 0; ct < 8; ++ct) acc[ct] = (floatx4){0.f, 0.f, 0.f, 0.f};

    for (int kc = 0; kc < 2; ++kc) {
        __syncthreads();
        for (int i = tid; i < 512; i += 256) {
            const int row = i >> 3, seg = i & 7;
            short8 o = {0, 0, 0, 0, 0, 0, 0, 0};
            if (row < 60) {
                const float* s = x + (size_t)nodes[row] * 128 + kc * 64 + seg * 8;
                const float4 f0 = *(const float4*)s;
                const float4 f1 = *(const float4*)(s + 4);
                o[0] = (short)f2bf(flog1p(f0.x)); o[1] = (short)f2bf(flog1p(f0.y));
                o[2] = (short)f2bf(flog1p(f0.z)); o[3] = (short)f2bf(flog1p(f0.w));
                o[4] = (short)f2bf(flog1p(f1.x)); o[5] = (short)f2bf(flog1p(f1.y));
                o[6] = (short)f2bf(flog1p(f1.z)); o[7] = (short)f2bf(flog1p(f1.w));
            }
            *(short8*)&aT[row * 72 + seg * 8] = o;
        }
        for (int i = tid; i < 1024; i += 256) {
            const int row = i >> 3, seg = i & 7;
            *(short8*)&wT[row * 72 + seg * 8] =
                *(const short8*)&Wpb[(size_t)row * 128 + kc * 64 + seg * 8];
        }
        __syncthreads();
#pragma unroll
        for (int k0 = 0; k0 < 64; k0 += 32) {
            const short8 a = *(const short8*)&aT[(wv * 16 + ml) * 72 + k0 + qk];
#pragma unroll
            for (int ct = 0; ct < 8; ++ct) {
                const short8 b = *(const short8*)&wT[(ct * 16 + ml) * 72 + k0 + qk];
                acc[ct] = __builtin_amdgcn_mfma_f32_16x16x32_bf16(a, b, acc[ct], 0, 0, 0);
            }
        }
    }
    __syncthreads();
#pragma unroll
    for (int ct = 0; ct < 8; ++ct) {
        const int col = ct * 16 + ml;
        const float bb = bp[col];
#pragma unroll
        for (int r = 0; r < 4; ++r) {
            const int row = wv * 16 + q * 4 + r;
            if (row < 60) {
                const float v = fmaxf(acc[ct][r] + bb, 0.0f);
                atomicMax(&red[(row / 15) * 128 + col], __float_as_uint(v));
            }
        }
    }
    __syncthreads();
    for (int i = tid; i < 512; i += 256)
        hnb[(size_t)blockIdx.x * 512 + i] = f2bf(__uint_as_float(red[i]));
}

// ---------------------------------------------------------------------------
// Stage B: h0 = [log1p(x[:N1]) | h_neigh] @ [Ws0|Wn0]^T + b0 (R1-proven),
// stored bf16 pre-BN, fused per-column sum/sumsq partials.
// ---------------------------------------------------------------------------
__global__ __launch_bounds__(256) void h0_kernel(
    const float* __restrict__ x, const unsigned short* __restrict__ hnb,
    const unsigned short* __restrict__ Ws0b, const unsigned short* __restrict__ Wn0b,
    const float* __restrict__ b0, unsigned short* __restrict__ h0bf,
    float* __restrict__ bn_sum, float* __restrict__ bn_sq)
{
    __shared__ unsigned short smem[64 * 72 + 128 * 72];
    unsigned short* aT = smem;
    unsigned short* wT = smem + 64 * 72;

    const int tid = threadIdx.x;
    const int m0 = blockIdx.x * 64, c0 = blockIdx.y * 128;
    const int lane = tid & 63, wv = tid >> 6;
    const int ml = lane & 15, q = lane >> 4, qk = q * 8;

    floatx4 acc[8];
#pragma unroll
    for (int ct = 0; ct < 8; ++ct) acc[ct] = (floatx4){0.f, 0.f, 0.f, 0.f};

    for (int kc = 0; kc < 4; ++kc) {
        __syncthreads();
        for (int i = tid; i < 512; i += 256) {
            const int row = i >> 3, seg = i & 7;
            const int k = kc * 64 + seg * 8;
            if (kc < 2) {
                const float* s = x + (size_t)(m0 + row) * 128 + k;
                const float4 f0 = *(const float4*)s;
                const float4 f1 = *(const float4*)(s + 4);
                short8 o;
                o[0] = (short)f2bf(flog1p(f0.x)); o[1] = (short)f2bf(flog1p(f0.y));
                o[2] = (short)f2bf(flog1p(f0.z)); o[3] = (short)f2bf(flog1p(f0.w));
                o[4] = (short)f2bf(flog1p(f1.x)); o[5] = (short)f2bf(flog1p(f1.y));
                o[6] = (short)f2bf(flog1p(f1.z)); o[7] = (short)f2bf(flog1p(f1.w));
                *(short8*)&aT[row * 72 + seg * 8] = o;
            } else {
                *(short8*)&aT[row * 72 + seg * 8] =
                    *(const short8*)&hnb[(size_t)(m0 + row) * 128 + (k - 128)];
            }
        }
        for (int i = tid; i < 1024; i += 256) {
            const int row = i >> 3, seg = i & 7;
            const int k = kc * 64 + seg * 8;
            const size_t cg = (size_t)(c0 + row);
            *(short8*)&wT[row * 72 + seg * 8] = (kc < 2)
                ? *(const short8*)&Ws0b[cg * 128 + k]
                : *(const short8*)&Wn0b[cg * 128 + (k - 128)];
        }
        __syncthreads();
#pragma unroll
        for (int k0 = 0; k0 < 64; k0 += 32) {
            const short8 a = *(const short8*)&aT[(wv * 16 + ml) * 72 + k0 + qk];
#pragma unroll
            for (int ct = 0; ct < 8; ++ct) {
                const short8 b = *(const short8*)&wT[(ct * 16 + ml) * 72 + k0 + qk];
                acc[ct] = __builtin_amdgcn_mfma_f32_16x16x32_bf16(a, b, acc[ct], 0, 0, 0);
            }
        }
    }
    __syncthreads();
    float* scr = (float*)smem;   // 4096 floats = 16 KB
#pragma unroll
    for (int ct = 0; ct < 8; ++ct) {
        const int col = ct * 16 + ml, cg = c0 + col;
        const float bb = b0[cg];
        float s = 0.f, sq = 0.f;
#pragma unroll
        for (int r = 0; r < 4; ++r) {
            const int row = wv * 16 + q * 4 + r;
            const float v = acc[ct][r] + bb;
            h0bf[(size_t)(m0 + row) * 256 + cg] = f2bf(v);
            s += v; sq += v * v;
        }
        scr[(wv * 4 + q) * 128 + col] = s;
        scr[2048 + (wv * 4 + q) * 128 + col] = sq;
    }
    __syncthreads();
    if (tid < 128) {
        float s = 0.f, sq = 0.f;
#pragma unroll
        for (int j = 0; j < 16; ++j) {
            s += scr[j * 128 + tid];
            sq += scr[2048 + j * 128 + tid];
        }
        atomicAdd(&bn_sum[c0 + tid], s);
        atomicAdd(&bn_sq[c0 + tid], sq);
    }
}

// ---------------------------------------------------------------------------
// bn_apply with stats folded in (each block recomputes scale/shift in f32 —
// same formula as the old bn_stats -> bit-identical).
// ---------------------------------------------------------------------------
__global__ __launch_bounds__(256) void bn_apply_kernel(
    const unsigned short* __restrict__ h0bf, const float* __restrict__ bn_sum,
    const float* __restrict__ bn_sq, const float* __restrict__ gamma,
    const float* __restrict__ beta, unsigned short* __restrict__ h0nbf)
{
    __shared__ float sc[256], sh[256];
    const int tid = threadIdx.x;
    {
        const float inv_n = 1.0f / (float)N1v;
        const float mu = bn_sum[tid] * inv_n;
        const float var = bn_sq[tid] * inv_n - mu * mu;
        const float rs = rsqrtf(var + 1e-5f);
        const float s = rs * gamma[tid];
        sc[tid] = s;
        sh[tid] = beta[tid] - mu * s;
    }
    __syncthreads();
    const int gid = blockIdx.x * 256 + tid;   // over N1*256/8
    const int c0 = (gid * 8) & 255;
    const short8 v = *(const short8*)&h0bf[(size_t)gid * 8];
    short8 o;
#pragma unroll
    for (int j = 0; j < 8; ++j) {
        const float f = bf2f((unsigned short)v[j]);
        o[j] = (short)f2bf(fmaxf(fmaf(f, sc[c0 + j], sh[c0 + j]), 0.0f));
    }
    *(short8*)&h0nbf[(size_t)gid * 8] = o;
}

// ---------------------------------------------------------------------------
// Fused LSTM step — R9's measured-best geometry: grid (64,16) = 1024 blocks
// (4/CU, 16 waves/CU) with 128-K chunks (4 chunks; t=0: 2), 8 barriers/step.
// Block = 64 rows x 16 h-cols x 4 gates; per-thread acc[4] = i,f,g,o for one
// (row, h-col) -> pointwise in registers. LDS 34.8 KB.
// ---------------------------------------------------------------------------
__global__ __launch_bounds__(256) void lstm_step_kernel(
    const unsigned short* __restrict__ h0nbf, const int* __restrict__ nbr1,
    const unsigned short* __restrict__ hbprev, const unsigned short* __restrict__ Wihb,
    const unsigned short* __restrict__ Whhb, const float* __restrict__ bsum,
    float* __restrict__ cst, unsigned short* __restrict__ hb, int t)
{
    __shared__ unsigned short aT[64 * 136];   // 17,408 B
    __shared__ unsigned short wT[64 * 136];   // 17,408 B
    __shared__ int nodes[64];

    const int tid = threadIdx.x;
    const int m0 = blockIdx.x * 64, c0h = blockIdx.y * 16;
    const int lane = tid & 63, wv = tid >> 6;
    const int ml = lane & 15, q = lane >> 4, qk = q * 8;

    if (tid < 64) nodes[tid] = nbr1[(size_t)(m0 + tid) * 10 + t];

    floatx4 acc[4];
#pragma unroll
    for (int ct = 0; ct < 4; ++ct) acc[ct] = (floatx4){0.f, 0.f, 0.f, 0.f};

    const int kcN = (t == 0) ? 2 : 4;   // 128-K chunks; h_prev == 0 at t=0
    for (int kc = 0; kc < kcN; ++kc) {
        __syncthreads();
        for (int i = tid; i < 1024; i += 256) {           // A: 64 rows x 128 k
            const int row = i >> 4, seg = i & 15;
            const int k = kc * 128 + seg * 8;
            *(short8*)&aT[row * 136 + seg * 8] = (k < 256)
                ? *(const short8*)&h0nbf[(size_t)nodes[row] * 256 + k]
                : *(const short8*)&hbprev[(size_t)(m0 + row) * 256 + (k - 256)];
        }
        for (int i = tid; i < 1024; i += 256) {           // W: 64 gate-rows x 128 k
            const int row = i >> 4, seg = i & 15;         // gate=row>>4, hc=row&15
            const int k = kc * 128 + seg * 8;
            const size_t wr = (size_t)((row >> 4) * 256 + c0h + (row & 15));
            *(short8*)&wT[row * 136 + seg * 8] = (k < 256)
                ? *(const short8*)&Wihb[wr * 256 + k]
                : *(const short8*)&Whhb[wr * 256 + (k - 256)];
        }
        __syncthreads();
#pragma unroll
        for (int k0 = 0; k0 < 128; k0 += 32) {
            const short8 a = *(const short8*)&aT[(wv * 16 + ml) * 136 + k0 + qk];
#pragma unroll
            for (int ct = 0; ct < 4; ++ct) {
                const short8 b = *(const short8*)&wT[(ct * 16 + ml) * 136 + k0 + qk];
                acc[ct] = __builtin_amdgcn_mfma_f32_16x16x32_bf16(a, b, acc[ct], 0, 0, 0);
            }
        }
    }
    // pointwise LSTM epilogue: acc[0..3] = i,f,g,o for (row, c0h+ml)
    const int hcol = c0h + ml;
    const float bi = bsum[hcol];
    const float bf_ = bsum[256 + hcol];
    const float bg = bsum[512 + hcol];
    const float bo = bsum[768 + hcol];
#pragma unroll
    for (int r = 0; r < 4; ++r) {
        const int row = wv * 16 + q * 4 + r;
        const size_t idx = (size_t)(m0 + row) * 256 + hcol;
        const float gi = acc[0][r] + bi;
        const float gf = acc[1][r] + bf_;
        const float gg = acc[2][r] + bg;
        const float go = acc[3][r] + bo;
        float c = sigf(gi) * tanhfast(gg);
        if (t > 0) c += sigf(gf) * cst[idx];
        cst[idx] = c;
        hb[idx] = f2bf(sigf(go) * tanhfast(c));
    }
}

// Stage E: out = h0n[:B] @ W_self1^T + hT @ W_neigh1^T + b1   [4096 x 32]
__global__ __launch_bounds__(256) void out_kernel(
    const unsigned short* __restrict__ h0nbf, const unsigned short* __restrict__ hTb,
    const float* __restrict__ Ws1, const float* __restrict__ Wn1,
    const float* __restrict__ b1, float* __restrict__ out)
{
    const int gid = blockIdx.x * 256 + threadIdx.x;   // < 4096*32
    const int row = gid >> 5, c = gid & 31;
    const unsigned short* a0 = h0nbf + (size_t)row * 256;
    const unsigned short* a1 = hTb + (size_t)row * 256;
    const float* w0 = Ws1 + (size_t)c * 256;
    const float* w1 = Wn1 + (size_t)c * 256;
    float s = b1[c];
#pragma unroll 4
    for (int k8 = 0; k8 < 32; ++k8) {
        const short8 av = *(const short8*)&a0[k8 * 8];
        const short8 bv = *(const short8*)&a1[k8 * 8];
        const float4 wa0 = *(const float4*)&w0[k8 * 8];
        const float4 wa1 = *(const float4*)&w0[k8 * 8 + 4];
        const float4 wb0 = *(const float4*)&w1[k8 * 8];
        const float4 wb1 = *(const float4*)&w1[k8 * 8 + 4];
        s += bf2f((unsigned short)av[0]) * wa0.x + bf2f((unsigned short)av[1]) * wa0.y;
        s += bf2f((unsigned short)av[2]) * wa0.z + bf2f((unsigned short)av[3]) * wa0.w;
        s += bf2f((unsigned short)av[4]) * wa1.x + bf2f((unsigned short)av[5]) * wa1.y;
        s += bf2f((unsigned short)av[6]) * wa1.z + bf2f((unsigned short)av[7]) * wa1.w;
        s += bf2f((unsigned short)bv[0]) * wb0.x + bf2f((unsigned short)bv[1]) * wb0.y;
        s += bf2f((unsigned short)bv[2]) * wb0.z + bf2f((unsigned short)bv[3]) * wb0.w;
        s += bf2f((unsigned short)bv[4]) * wb1.x + bf2f((unsigned short)bv[5]) * wb1.y;
        s += bf2f((unsigned short)bv[6]) * wb1.z + bf2f((unsigned short)bv[7]) * wb1.w;
    }
    out[gid] = s;
}

extern "C" void kernel_launch(void* const* d_in, const int* in_sizes, int n_in,
                              void* d_out, int out_size, void* d_ws, size_t ws_size,
                              hipStream_t stream)
{
    const float* x        = (const float*)d_in[0];
    const int*   nbr0     = (const int*)d_in[1];
    const int*   nbr1     = (const int*)d_in[2];
    const float* W_pool   = (const float*)d_in[3];
    const float* b_pool   = (const float*)d_in[4];
    const float* W_self0  = (const float*)d_in[5];
    const float* W_neigh0 = (const float*)d_in[6];
    const float* b0       = (const float*)d_in[7];
    const float* gamma0   = (const float*)d_in[8];
    const float* beta0    = (const float*)d_in[9];
    const float* W_ih     = (const float*)d_in[10];
    const float* W_hh     = (const float*)d_in[11];
    const float* b_ih     = (const float*)d_in[12];
    const float* b_hh     = (const float*)d_in[13];
    const float* W_self1  = (const float*)d_in[14];
    const float* W_neigh1 = (const float*)d_in[15];
    const float* b1       = (const float*)d_in[16];
    float* out = (float*)d_out;

    char* ws = (char*)d_ws;
    const size_t NEED_BIG = 168990720;   // big path: hnb + hp(157MB, aliased) + weights
    const bool big = (ws_size >= NEED_BIG);

    unsigned short *h0bf, *hnb, *h0nbf, *hb0, *hb1, *Wpb, *Ws0b, *Wn0b, *Wihb, *Whhb, *hpb;
    float *cst, *bsum, *bn_sum, *bn_sq;

    if (big) {
        hnb   = (unsigned short*)(ws);                    // 10,485,760
        hpb   = (unsigned short*)(ws + 10485760);         // 157,286,400 (dead after gather)
        h0bf  = (unsigned short*)(ws + 10485760);         //  20,971,520 (alias)
        h0nbf = (unsigned short*)(ws + 31457280);         //  20,971,520 (alias)
        cst   = (float*)         (ws + 52428800);         //   4,194,304 (alias)
        hb0   = (unsigned short*)(ws + 56623104);         //   2,097,152 (alias)
        hb1   = (unsigned short*)(ws + 58720256);         //   2,097,152 (alias)
        Wpb   = (unsigned short*)(ws + 167772160);
        Ws0b  = (unsigned short*)(ws + 167804928);
        Wn0b  = (unsigned short*)(ws + 167870464);
        Wihb  = (unsigned short*)(ws + 167936000);
        Whhb  = (unsigned short*)(ws + 168460288);
        bsum  = (float*)         (ws + 168984576);
        bn_sum= (float*)         (ws + 168988672);
        bn_sq = (float*)         (ws + 168989696);
    } else {
        h0bf  = (unsigned short*)(ws);
        hnb   = (unsigned short*)(ws + 20971520);
        h0nbf = (unsigned short*)(ws + 31457280);
        cst   = (float*)         (ws + 52428800);
        hb0   = (unsigned short*)(ws + 56623104);
        hb1   = (unsigned short*)(ws + 58720256);
        Wpb   = (unsigned short*)(ws + 60817408);
        Ws0b  = (unsigned short*)(ws + 60850176);
        Wn0b  = (unsigned short*)(ws + 60915712);
        Wihb  = (unsigned short*)(ws + 60981248);
        Whhb  = (unsigned short*)(ws + 61505536);
        bsum  = (float*)         (ws + 62029824);
        bn_sum= (float*)         (ws + 62033920);
        bn_sq = (float*)         (ws + 62034944);
        hpb   = 0;
    }

    // bn_sum/bn_sq zero-init folded into cvt_weights (bn_sum,bn_sq adjacent).
    cvt_weights_kernel<<<2374, 256, 0, stream>>>(W_pool, W_self0, W_neigh0, W_ih, W_hh,
                                                 b_ih, b_hh, Wpb, Ws0b, Wn0b, Wihb, Whhb,
                                                 bsum, bn_sum);
    if (big) {
        pool_dense_kernel<<<N0v / 64, 256, 0, stream>>>(x, Wpb, b_pool, hpb);
        pool_gather_kernel<<<(N1v * 64) / 256, 256, 0, stream>>>(hpb, nbr0, hnb);
    } else {
        pool_max_kernel<<<N1v / 4, 256, 0, stream>>>(x, nbr0, Wpb, b_pool, hnb);
    }
    h0_kernel<<<dim3(N1v / 64, 2), 256, 0, stream>>>(x, hnb, Ws0b, Wn0b, b0,
                                                     h0bf, bn_sum, bn_sq);
    bn_apply_kernel<<<(N1v * 256 / 8) / 256, 256, 0, stream>>>(h0bf, bn_sum, bn_sq,
                                                               gamma0, beta0, h0nbf);

    for (int t = 0; t < 10; ++t) {
        const unsigned short* hp = (t & 1) ? hb1 : hb0;
        unsigned short*       hn = (t & 1) ? hb0 : hb1;
        lstm_step_kernel<<<dim3(BATCHv / 64, 16), 256, 0, stream>>>(
            h0nbf, nbr1, hp, Wihb, Whhb, bsum, cst, hn, t);
    }
    // t=9 wrote hb0 -> final hidden state
    out_kernel<<<(BATCHv * 32) / 256, 256, 0, stream>>>(h0nbf, hb0, W_self1, W_neigh1, b1, out);
}